// Round 5
// baseline (6044.780 us; speedup 1.0000x reference)
//
#include <hip/hip_runtime.h>

#define HID    1024
#define DVID   4096
#define DWORD  512
#define XLEN   (HID + DWORD)
#define NVOCAB 32000
#define NSTEP  39          // MAX_LEN - 1
#define NT     256
#define NWPB   4
#define NEG_BIG (-3.402823466e38f)

// logits GEMM decomposition
#define TG      8                    // t's per group
#define NTGRP   5                    // groups: 8,8,8,8,7
#define NRB     125                  // row-blocks of 256 rows (125*256 = 32000)
#define NJOBS   (NRB * NTGRP)        // 625
#define NSLICE  26                   // softmax offset slices per t
#define SLICE_W 1231                 // 26*1231 >= 32000
#define NOFF    (NSTEP * NSLICE)     // 1014

// ---- workspace layout (bytes) ----
#define CTRL_BYTES 65536
#define RBAR_W   0                   // rec barrier counter (word idx)
#define H2F_W    256                 // done-flag replicas: word 256 + i*32, i<8
#define LBAR_W   1024                // final barrier sub-counters: word 1024 + i*32
#define G1_OFF   65536               // [2][4096] f
#define G2A_OFF  (G1_OFF  + 32768)   // [2][4096] f
#define G2B_OFF  (G2A_OFF + 32768)   // [2][4096] f
#define H2B_OFF  (G2B_OFF + 32768)   // [39][1024] f
#define PM_OFF   (H2B_OFF + 159744)  // [39][128] f
#define PS_OFF   (PM_OFF  + 19968)   // [39][128] f
#define W16T_OFF (PS_OFF  + 19968)   // bf16 w_out TRANSPOSED [1024][32000]
#define W16T_BYTES ((size_t)HID * NVOCAB * 2)
#define WS_NEED  ((size_t)W16T_OFF + W16T_BYTES)

__device__ __forceinline__ float fast_sigmoid(float x) { return 1.f / (1.f + __expf(-x)); }
__device__ __forceinline__ float fast_tanh(float x)    { return 1.f - 2.f / (__expf(2.f * x) + 1.f); }

__device__ __forceinline__ float wave_reduce(float v) {
#pragma unroll
    for (int o = 32; o; o >>= 1) v += __shfl_xor(v, o, 64);
    return v;
}
__device__ __forceinline__ int wave_reduce_i(int v) {
#pragma unroll
    for (int o = 32; o; o >>= 1) v += __shfl_xor(v, o, 64);
    return v;
}

__device__ __forceinline__ void smax_comb(float& M, float& S, float m2, float s2) {
    float nm = fmaxf(M, m2);
    S = S * __expf(M - nm) + s2 * __expf(m2 - nm);
    M = nm;
}
__device__ __forceinline__ void online_upd(float& m, float& s, float v) {
    if (v > m) { s = s * __expf(m - v) + 1.f; m = v; } else s += __expf(v - m);
}

template<int LEN>
__device__ __forceinline__ float row_dotT(const float* __restrict__ w, const float* x, int lane) {
    float a = 0.f;
#pragma unroll
    for (int q = lane * 4; q < LEN; q += 256) {
        float4 wv = *(const float4*)(w + q);
        float4 xv = *(const float4*)(x + q);
        a = fmaf(wv.x, xv.x, a); a = fmaf(wv.y, xv.y, a);
        a = fmaf(wv.z, xv.z, a); a = fmaf(wv.w, xv.w, a);
    }
    return wave_reduce(a);
}

// two independent LEN-dots, loads interleaved (2x load ILP)
template<int LEN>
__device__ __forceinline__ void row_dot2T(const float* __restrict__ wa, const float* xa,
                                          const float* __restrict__ wb, const float* xb,
                                          int lane, float& ra, float& rb) {
    float a = 0.f, b = 0.f;
#pragma unroll
    for (int q = lane * 4; q < LEN; q += 256) {
        float4 w1 = *(const float4*)(wa + q);
        float4 w2 = *(const float4*)(wb + q);
        float4 x1 = *(const float4*)(xa + q);
        float4 x2 = *(const float4*)(xb + q);
        a = fmaf(w1.x, x1.x, a); a = fmaf(w1.y, x1.y, a);
        a = fmaf(w1.z, x1.z, a); a = fmaf(w1.w, x1.w, a);
        b = fmaf(w2.x, x2.x, b); b = fmaf(w2.y, x2.y, b);
        b = fmaf(w2.z, x2.z, b); b = fmaf(w2.w, x2.w, b);
    }
    ra = wave_reduce(a); rb = wave_reduce(b);
}

__device__ __forceinline__ void lstm_update1(const float* __restrict__ G, float* c, float* h, int tid) {
    for (int j = tid; j < HID; j += NT) {
        float gi = G[j], gf = G[j + HID], gg = G[j + 2 * HID], go = G[j + 3 * HID];
        float cn = fast_sigmoid(gf) * c[j] + fast_sigmoid(gi) * fast_tanh(gg);
        c[j] = cn;
        h[j] = fast_sigmoid(go) * fast_tanh(cn);
    }
}
__device__ __forceinline__ void lstm_update2(const float* __restrict__ Ga, const float* __restrict__ Gb,
                                             float* c, float* h, int tid) {
    for (int j = tid; j < HID; j += NT) {
        float gi = Ga[j] + Gb[j];
        float gf = Ga[j + HID] + Gb[j + HID];
        float gg = Ga[j + 2 * HID] + Gb[j + 2 * HID];
        float go = Ga[j + 3 * HID] + Gb[j + 3 * HID];
        float cn = fast_sigmoid(gf) * c[j] + fast_sigmoid(gi) * fast_tanh(gg);
        c[j] = cn;
        h[j] = fast_sigmoid(go) * fast_tanh(cn);
    }
}

__device__ __forceinline__ void rec_barrier(unsigned* ctr, unsigned target, int tid) {
    __syncthreads();
    if (tid == 0) {
        __threadfence();
        __hip_atomic_fetch_add(ctr, 1u, __ATOMIC_RELEASE, __HIP_MEMORY_SCOPE_AGENT);
        while (__hip_atomic_load(ctr, __ATOMIC_ACQUIRE, __HIP_MEMORY_SCOPE_AGENT) < target)
            __builtin_amdgcn_s_sleep(8);
        __threadfence();
    }
    __syncthreads();
}

__device__ __forceinline__ unsigned short f2bf(float f) {
    unsigned u = __float_as_uint(f);
    u += 0x7fffu + ((u >> 16) & 1u);   // RNE
    return (unsigned short)(u >> 16);
}

// w_out [32000][1024] fp32 -> wT [1024][32000] bf16 (64x64 LDS tiles)
__global__ __launch_bounds__(256) void tcvt_kernel(const float* __restrict__ w,
                                                   unsigned short* __restrict__ o) {
    __shared__ unsigned short sT[64][72];
    const int tid = threadIdx.x;
    const int r0 = blockIdx.x * 64, k0 = blockIdx.y * 64;
    const int rr = tid >> 2, kc = (tid & 3) * 16;
    const float* src = w + (size_t)(r0 + rr) * HID + k0 + kc;
#pragma unroll
    for (int i = 0; i < 4; ++i) {
        float4 v = *(const float4*)(src + 4 * i);
        sT[kc + 4 * i + 0][rr] = f2bf(v.x);
        sT[kc + 4 * i + 1][rr] = f2bf(v.y);
        sT[kc + 4 * i + 2][rr] = f2bf(v.z);
        sT[kc + 4 * i + 3][rr] = f2bf(v.w);
    }
    __syncthreads();
    const int kk = tid >> 2, rc = (tid & 3) * 16;
    unsigned q[8];
#pragma unroll
    for (int i = 0; i < 8; ++i)
        q[i] = (unsigned)sT[kk][rc + 2 * i] | ((unsigned)sT[kk][rc + 2 * i + 1] << 16);
    unsigned short* dst = o + (size_t)(k0 + kk) * NVOCAB + r0 + rc;
    *(uint4*)(dst)     = make_uint4(q[0], q[1], q[2], q[3]);
    *(uint4*)(dst + 8) = make_uint4(q[4], q[5], q[6], q[7]);
}

__global__ __launch_bounds__(NT, 4) void seq2seq_kernel(
    const float* __restrict__ vid,
    const float* __restrict__ w_ih1, const float* __restrict__ w_hh1,
    const float* __restrict__ b_ih1, const float* __restrict__ b_hh1,
    const float* __restrict__ w_ih2, const float* __restrict__ w_hh2,
    const float* __restrict__ b_ih2, const float* __restrict__ b_hh2,
    const float* __restrict__ emb,  const float* __restrict__ w_out,
    const float* __restrict__ b_out,
    int use16, int nr,
    float* __restrict__ out, char* wsb)
{
    const int tid  = threadIdx.x;
    const int lane = tid & 63;
    const int wib  = tid >> 6;
    const int nb   = gridDim.x;

    unsigned* ctrl = (unsigned*)wsb;
    unsigned* rbar = ctrl + RBAR_W;
    unsigned* h2f  = ctrl + H2F_W;
    unsigned* lbar = ctrl + LBAR_W;
    float* G1g = (float*)(wsb + G1_OFF);
    float* G2a = (float*)(wsb + G2A_OFF);
    float* G2b = (float*)(wsb + G2B_OFF);
    float* h2b = (float*)(wsb + H2B_OFF);
    float* PM  = (float*)(wsb + PM_OFF);
    float* PS  = (float*)(wsb + PS_OFF);
    const unsigned short* w16T = (const unsigned short*)(wsb + W16T_OFF);

    __shared__ float smem[8192];              // GEMM h2-tile / rec vectors / fallback h2
    __shared__ float sPm[NWPB][TG], sPs[NWPB][TG];
    __shared__ float sRm[NWPB], sRs[NWPB];
    __shared__ int   sRi[NWPB];
    __shared__ int   sIdx;

    if (blockIdx.x < nr) {
        //==================== RECURRENCE (nr blocks, 1 per CU) ====================
        float* sX  = smem;                     // [XLEN]
        float* sC1 = smem + 1536;
        float* sC2 = smem + 2560;
        float* sH2 = smem + 3584;
        const int nwr = nr * NWPB;
        const int gw  = blockIdx.x * NWPB + wib;
        unsigned bk = 0;

        for (int j = tid; j < HID; j += NT) { sC1[j] = 0.f; sC2[j] = 0.f; }
        if (tid == 0) sIdx = 0;
        __syncthreads();

        // E1: G1_e = b1s + vid @ w_ih1^T -> slot 1
        {
            int chunk = (4096 + nwr - 1) / nwr;
            int b0 = gw * chunk, e0 = b0 + chunk; if (e0 > 4096) e0 = 4096;
            for (int r = b0; r < e0; ++r) {
                float v = row_dotT<DVID>(w_ih1 + (size_t)r * DVID, vid, lane);
                if (lane == 0) G1g[4096 + r] = v + b_ih1[r] + b_hh1[r];
            }
        }
        rec_barrier(rbar, nr * (++bk), tid);

        // E2: h1_e; G2a_e (slot1), G2b_e = 0; G1(0) -> slot 0
        lstm_update1(G1g + 4096, sC1, sX, tid);
        for (int j = tid; j < DWORD; j += NT) sX[HID + j] = 0.f;
        __syncthreads();
        {
            int chunk = (8192 + nwr - 1) / nwr;
            int b0 = gw * chunk, e0 = b0 + chunk; if (e0 > 8192) e0 = 8192;
            for (int task = b0; task < e0; ++task) {
                if (task < 4096) {
                    int r = task;
                    float v = row_dotT<XLEN>(w_ih2 + (size_t)r * XLEN, sX, lane);
                    if (lane == 0) G2a[4096 + r] = v + b_ih2[r] + b_hh2[r];
                } else {
                    int r = task - 4096;
                    float v = row_dotT<HID>(w_hh1 + (size_t)r * HID, sX, lane);
                    if (lane == 0) { G1g[r] = v + b_ih1[r] + b_hh1[r]; G2b[4096 + r] = 0.f; }
                }
            }
        }
        rec_barrier(rbar, nr * (++bk), tid);

        // E3: h2_e (c2 = 0)
        lstm_update2(G2a + 4096, G2b + 4096, sC2, sH2, tid);
        __syncthreads();

        for (int t = 0; t < NSTEP; ++t) {
            const int cb = (t & 1) * 4096, nb2 = ((t + 1) & 1) * 4096;
            lstm_update1(G1g + cb, sC1, sX, tid);
            {
                const float* erow = emb + (size_t)sIdx * DWORD;
                for (int j = tid; j < DWORD; j += NT) sX[HID + j] = erow[j];
            }
            __syncthreads();
            {
                int chunk = (8192 + nwr - 1) / nwr;
                int b0 = gw * chunk, e0 = b0 + chunk; if (e0 > 8192) e0 = 8192;
                int task = b0;
                while (task < e0) {
                    if (task < 4096) {
                        int r = task;
                        if (task + 1 < e0 && task + 1 < 4096) {
                            float v0, v1;
                            row_dot2T<XLEN>(w_ih2 + (size_t)r * XLEN, sX,
                                            w_ih2 + (size_t)(r + 1) * XLEN, sX, lane, v0, v1);
                            if (lane == 0) {
                                G2a[cb + r]     = v0 + b_ih2[r] + b_hh2[r];
                                G2a[cb + r + 1] = v1 + b_ih2[r + 1] + b_hh2[r + 1];
                            }
                            task += 2;
                        } else {
                            float v = row_dotT<XLEN>(w_ih2 + (size_t)r * XLEN, sX, lane);
                            if (lane == 0) G2a[cb + r] = v + b_ih2[r] + b_hh2[r];
                            task += 1;
                        }
                    } else {
                        int r = task - 4096;
                        float va, vb;
                        row_dot2T<HID>(w_hh2 + (size_t)r * HID, sH2,
                                       w_hh1 + (size_t)r * HID, sX, lane, va, vb);
                        if (lane == 0) {
                            G2b[cb + r] = va;
                            if (t < NSTEP - 1) G1g[nb2 + r] = vb + b_ih1[r] + b_hh1[r];
                        }
                        task += 1;
                    }
                }
            }
            rec_barrier(rbar, nr * (++bk), tid);

            lstm_update2(G2a + cb, G2b + cb, sC2, sH2, tid);
            __syncthreads();
            if (blockIdx.x == 0)
                for (int i = tid * 4; i < HID; i += NT * 4)
                    *(float4*)(h2b + (size_t)t * HID + i) = *(const float4*)(sH2 + i);
            {   // argmax(h2) -> sIdx (block-local, bit-identical across blocks)
                float bm = NEG_BIG; int bi = 0;
                for (int j = tid; j < HID; j += NT) {
                    float v = sH2[j];
                    if (v > bm) { bm = v; bi = j; }
                }
#pragma unroll
                for (int o = 32; o; o >>= 1) {
                    float vm = __shfl_xor(bm, o, 64); int vi = __shfl_xor(bi, o, 64);
                    if (vm > bm || (vm == bm && vi < bi)) { bm = vm; bi = vi; }
                }
                if (lane == 0) { sRm[wib] = bm; sRi[wib] = bi; }
                __syncthreads();
                if (tid == 0) {
                    float m0 = sRm[0]; int i0 = sRi[0];
                    for (int w = 1; w < NWPB; ++w)
                        if (sRm[w] > m0 || (sRm[w] == m0 && sRi[w] < i0)) { m0 = sRm[w]; i0 = sRi[w]; }
                    sIdx = i0;
                }
            }
            __syncthreads();
        }
        // publish "all h2 ready"
        if (blockIdx.x == 0 && tid == 0) {
            __threadfence();
#pragma unroll
            for (int i = 0; i < 8; ++i)
                __hip_atomic_store(h2f + i * 32, (unsigned)NSTEP,
                                   __ATOMIC_RELEASE, __HIP_MEMORY_SCOPE_AGENT);
        }
        __syncthreads();
    }

    //==================== everyone: wait for h2 complete ====================
    if (tid == 0) {
        unsigned* f = h2f + (blockIdx.x & 7) * 32;
        while (__hip_atomic_load(f, __ATOMIC_ACQUIRE, __HIP_MEMORY_SCOPE_AGENT) < (unsigned)NSTEP)
            __builtin_amdgcn_s_sleep(32);
        __threadfence();
    }
    __syncthreads();

    //==================== logits ====================
    if (use16) {
        float* sH = smem;    // [1024][TG]
        for (int job = blockIdx.x; job < NJOBS; job += nb) {
            const int rb = job % NRB, tg = job / NRB;
            const int t0 = tg * TG;
            const int tcnt = (tg == NTGRP - 1) ? (NSTEP - t0) : TG;
            __syncthreads();
#pragma unroll
            for (int j = 0; j < TG; ++j) {
                if (j < tcnt) {
                    const float* hsrc = h2b + (size_t)(t0 + j) * HID;
                    for (int k = tid; k < HID; k += NT) sH[k * TG + j] = hsrc[k];
                } else {
                    for (int k = tid; k < HID; k += NT) sH[k * TG + j] = 0.f;
                }
            }
            __syncthreads();
            const int r = rb * NT + tid;
            const unsigned short* wp = w16T + r;
            float acc[TG];
#pragma unroll
            for (int j = 0; j < TG; ++j) acc[j] = 0.f;
#pragma unroll 8
            for (int k = 0; k < HID; ++k) {
                float wv = __uint_as_float((unsigned)wp[(size_t)k * NVOCAB] << 16);
                float4 h0 = *(const float4*)(sH + k * TG);
                float4 h1 = *(const float4*)(sH + k * TG + 4);
                acc[0] = fmaf(wv, h0.x, acc[0]); acc[1] = fmaf(wv, h0.y, acc[1]);
                acc[2] = fmaf(wv, h0.z, acc[2]); acc[3] = fmaf(wv, h0.w, acc[3]);
                acc[4] = fmaf(wv, h1.x, acc[4]); acc[5] = fmaf(wv, h1.y, acc[5]);
                acc[6] = fmaf(wv, h1.z, acc[6]); acc[7] = fmaf(wv, h1.w, acc[7]);
            }
            const float bias = b_out[r];
#pragma unroll
            for (int j = 0; j < TG; ++j) {
                if (j >= tcnt) break;
                float v = acc[j] + bias;
                out[(size_t)(t0 + j) * NVOCAB + r] = v;
                float m = v, s = 1.f;
#pragma unroll
                for (int o = 32; o; o >>= 1) {
                    float m2 = __shfl_xor(m, o, 64), s2 = __shfl_xor(s, o, 64);
                    smax_comb(m, s, m2, s2);
                }
                if (lane == 0) { sPm[wib][j] = m; sPs[wib][j] = s; }
            }
            __syncthreads();
            if (tid < tcnt) {
                float M = sPm[0][tid], S = sPs[0][tid];
                for (int w = 1; w < NWPB; ++w) smax_comb(M, S, sPm[w][tid], sPs[w][tid]);
                PM[(t0 + tid) * 128 + rb] = M;
                PS[(t0 + tid) * 128 + rb] = S;
            }
            __syncthreads();
        }
    } else {
        // fallback: fp32 w_out, per-(t,slice) wave dots
        for (int id = blockIdx.x; id < NOFF; id += nb) {
            const int t = id / NSLICE, sl = id % NSLICE;
            __syncthreads();
            for (int k = tid; k < HID; k += NT) smem[k] = h2b[(size_t)t * HID + k];
            __syncthreads();
            const int begin = sl * SLICE_W;
            const int end = (begin + SLICE_W < NVOCAB) ? begin + SLICE_W : NVOCAB;
            float m = NEG_BIG, s = 0.f;
            for (int r = begin + wib; r < end; r += NWPB) {
                float v = row_dotT<HID>(w_out + (size_t)r * HID, smem, lane) + b_out[r];
                if (lane == 0) out[(size_t)t * NVOCAB + r] = v;
                online_upd(m, s, v);
            }
            if (lane == 0) { sPm[wib][0] = m; sPs[wib][0] = s; }
            __syncthreads();
            if (tid == 0) {
                float M = sPm[0][0], S = sPs[0][0];
                for (int w = 1; w < NWPB; ++w) smax_comb(M, S, sPm[w][0], sPs[w][0]);
                PM[t * 128 + sl] = M; PS[t * 128 + sl] = S;
            }
            __syncthreads();
        }
    }

    //==================== final grid barrier ====================
    __syncthreads();
    if (tid == 0) {
        __threadfence();
        __hip_atomic_fetch_add(lbar + (blockIdx.x & 7) * 32, 1u,
                               __ATOMIC_RELEASE, __HIP_MEMORY_SCOPE_AGENT);
    }
    if (wib == 0) {
        while (true) {
            unsigned v = (lane < 8)
                ? __hip_atomic_load(lbar + lane * 32, __ATOMIC_ACQUIRE, __HIP_MEMORY_SCOPE_AGENT)
                : 0u;
            if (wave_reduce_i((int)v) >= nb) break;
            __builtin_amdgcn_s_sleep(8);
        }
        if (lane == 0) __threadfence();
    }
    __syncthreads();

    //==================== log-softmax offset pass ====================
    {
        const int npart = use16 ? NRB : NSLICE;
        for (int id = blockIdx.x; id < NOFF; id += nb) {
            const int t = id / NSLICE, sl = id % NSLICE;
            float M = NEG_BIG, S = 0.f;
            for (int i = 0; i < npart; ++i) smax_comb(M, S, PM[t * 128 + i], PS[t * 128 + i]);
            const float off = M + __logf(S);
            const int begin = sl * SLICE_W;
            const int end = (begin + SLICE_W < NVOCAB) ? begin + SLICE_W : NVOCAB;
            float* orow = out + (size_t)t * NVOCAB;
            for (int i = begin + tid; i < end; i += NT) orow[i] -= off;
        }
    }
}

extern "C" void kernel_launch(void* const* d_in, const int* in_sizes, int n_in,
                              void* d_out, int out_size, void* d_ws, size_t ws_size,
                              hipStream_t stream) {
    const float* vid   = (const float*)d_in[0];
    const float* w_ih1 = (const float*)d_in[1];
    const float* w_hh1 = (const float*)d_in[2];
    const float* b_ih1 = (const float*)d_in[3];
    const float* b_hh1 = (const float*)d_in[4];
    const float* w_ih2 = (const float*)d_in[5];
    const float* w_hh2 = (const float*)d_in[6];
    const float* b_ih2 = (const float*)d_in[7];
    const float* b_hh2 = (const float*)d_in[8];
    const float* emb   = (const float*)d_in[9];
    const float* w_out = (const float*)d_in[10];
    const float* b_out = (const float*)d_in[11];
    float* out = (float*)d_out;
    char* wsb  = (char*)d_ws;

    int use16 = (ws_size >= WS_NEED) ? 1 : 0;

    hipMemsetAsync(d_ws, 0, CTRL_BYTES, stream);

    if (use16) {
        tcvt_kernel<<<dim3(NVOCAB / 64, HID / 64), dim3(256), 0, stream>>>(
            w_out, (unsigned short*)(wsb + W16T_OFF));
    }

    int occ = 0;
    if (hipOccupancyMaxActiveBlocksPerMultiprocessor(&occ, seq2seq_kernel, NT, 0) != hipSuccess || occ < 1)
        occ = 1;
    int nb = occ * 256;
    if (nb > 1024) nb = 1024;
    int nr = (nb >= 1024) ? 256 : (nb / 4 < 4 ? 4 : nb / 4);

    void* args[] = { &vid, &w_ih1, &w_hh1, &b_ih1, &b_hh1,
                     &w_ih2, &w_hh2, &b_ih2, &b_hh2,
                     &emb, &w_out, &b_out, &use16, &nr, &out, &wsb };
    hipLaunchCooperativeKernel((const void*)seq2seq_kernel,
                               dim3(nb), dim3(NT), args, 0, stream);
}